// Round 1
// 1235.922 us; speedup vs baseline: 1.2096x; 1.2096x over previous
//
#include <hip/hip_runtime.h>
#include <math.h>

// FusionRestormerBlock — bf16 MFMA, fragment-ordered weights.
// Tokenized layout: row = wid*64 + l (l = hi*8+wi), 192 channels contiguous.
// Weights stored as 16(N)x32(K) tiles in MFMA B-fragment order: 512 bf16 per tile,
// element [lane*8+j] = W[n = nt*16 + (lane&15)][k = kt*32 + (lane>>4)*8 + j]
// -> B-frag load is base + tile*1024B + lane*16B, fully coalesced.
// MFMA 16x16x32 bf16 C/D: col=lane&15, row=(lane>>4)*4+reg.

#define TPB 256
#define NWIN 2048
#define SCALEF 0.20412414523193154f  // 24^-0.5

typedef __attribute__((ext_vector_type(8))) short bhalf8;
typedef __attribute__((ext_vector_type(4))) float fvec4;

#define MFMA(a, b, c) __builtin_amdgcn_mfma_f32_16x16x32_bf16(a, b, c, 0, 0, 0)

__device__ __forceinline__ short f2bf(float f) {
    unsigned u = __float_as_uint(f);
    u = u + 0x7fffu + ((u >> 16) & 1u);
    return (short)(u >> 16);
}
__device__ __forceinline__ float bf2f(short s) {
    return __uint_as_float(((unsigned)(unsigned short)s) << 16);
}

// Weight region element counts (bf16 elements), all tile-packed
#define N_QKV 147456     // 8 heads x (6 nt x 6 kt) tiles
#define N_QC  49152      // 8 x (2 x 6)
#define N_KV  98304      // 8 x (4 x 6)
#define N_AP  36864      // 12 x 6
#define N_CP  36864
#define N_W1  147456     // 48 x 6
#define N_W2  147456     // 12 nt x 24 ks
#define W_TOT 663552

// ---------------- K0: weight prep (fp32 -> padded bf16, fragment-tile order) ----------------
__global__ __launch_bounds__(TPB) void k0_wprep(
    const float* __restrict__ qkvw, const float* __restrict__ qkvb,
    const float* __restrict__ qw, const float* __restrict__ kvw,
    const float* __restrict__ apw, const float* __restrict__ cpw,
    const float* __restrict__ w1, const float* __restrict__ w2,
    short* __restrict__ Wqkv, short* __restrict__ Wqc, short* __restrict__ Wkv,
    short* __restrict__ Wap, short* __restrict__ Wcp, short* __restrict__ W1b,
    short* __restrict__ W2b, float* __restrict__ qbp)
{
    const int tid = blockIdx.x * TPB + threadIdx.x;
    const int stride = gridDim.x * TPB;
    for (int i = tid; i < N_QKV; i += stride) {
        int tile = i >> 9, pos = i & 511;
        int lane = pos >> 3, j = pos & 7, l16 = lane & 15, g = lane >> 4;
        int h = tile / 36, t2 = tile % 36, nt = t2 / 6, kt = t2 % 6;
        int col = nt * 16 + l16, sub = col >> 5, d = col & 31;
        int k = kt * 32 + g * 8 + j;
        float v = (d < 24) ? qkvw[(sub * 192 + h * 24 + d) * 192 + k] : 0.f;
        Wqkv[i] = f2bf(v);
    }
    for (int i = tid; i < N_QC; i += stride) {
        int tile = i >> 9, pos = i & 511;
        int lane = pos >> 3, j = pos & 7, l16 = lane & 15, g = lane >> 4;
        int h = tile / 12, t2 = tile % 12, nt = t2 / 6, kt = t2 % 6;
        int col = nt * 16 + l16;
        int k = kt * 32 + g * 8 + j;
        float v = (col < 24) ? qw[(h * 24 + col) * 192 + k] : 0.f;
        Wqc[i] = f2bf(v);
    }
    for (int i = tid; i < N_KV; i += stride) {
        int tile = i >> 9, pos = i & 511;
        int lane = pos >> 3, j = pos & 7, l16 = lane & 15, g = lane >> 4;
        int h = tile / 24, t2 = tile % 24, nt = t2 / 6, kt = t2 % 6;
        int col = nt * 16 + l16, sub = col >> 5, d = col & 31;
        int k = kt * 32 + g * 8 + j;
        float v = (d < 24) ? kvw[(sub * 192 + h * 24 + d) * 192 + k] : 0.f;
        Wkv[i] = f2bf(v);
    }
    for (int i = tid; i < N_AP; i += stride) {
        int tile = i >> 9, pos = i & 511;
        int lane = pos >> 3, j = pos & 7, l16 = lane & 15, g = lane >> 4;
        int nt = tile / 6, kt = tile % 6;
        int n = nt * 16 + l16, k = kt * 32 + g * 8 + j;
        Wap[i] = f2bf(apw[n * 192 + k]);
    }
    for (int i = tid; i < N_CP; i += stride) {
        int tile = i >> 9, pos = i & 511;
        int lane = pos >> 3, j = pos & 7, l16 = lane & 15, g = lane >> 4;
        int nt = tile / 6, kt = tile % 6;
        int n = nt * 16 + l16, k = kt * 32 + g * 8 + j;
        Wcp[i] = f2bf(cpw[n * 192 + k]);
    }
    for (int i = tid; i < N_W1; i += stride) {
        int tile = i >> 9, pos = i & 511;
        int lane = pos >> 3, j = pos & 7, l16 = lane & 15, g = lane >> 4;
        int nt = tile / 6, kt = tile % 6;
        int n = nt * 16 + l16, k = kt * 32 + g * 8 + j;
        W1b[i] = f2bf(w1[n * 192 + k]);
    }
    for (int i = tid; i < N_W2; i += stride) {
        int tile = i >> 9, pos = i & 511;
        int lane = pos >> 3, j = pos & 7, l16 = lane & 15, g = lane >> 4;
        int nt = tile / 24, ks = tile % 24;
        int n = nt * 16 + l16, k = ks * 32 + g * 8 + j;
        W2b[i] = f2bf(w2[n * 768 + k]);
    }
    for (int i = tid; i < 768; i += stride) {
        int h = i / 96, col = i % 96, sub = col >> 5, d = col & 31;
        qbp[i] = (d < 24) ? qkvb[sub * 192 + h * 24 + d] : 0.f;
    }
}

// ---------------- K1: tokenize + cln1 ----------------
__global__ __launch_bounds__(TPB) void k1_prep(
    const float* __restrict__ xrgb, const float* __restrict__ xsar,
    const float* __restrict__ gamma, const float* __restrict__ beta,
    const float* __restrict__ ln1w, const float* __restrict__ ln1b,
    short* __restrict__ Ag, short* __restrict__ Xg, short* __restrict__ Sg)
{
    __shared__ float s_x[64 * 193];
    __shared__ float s_mu[64], s_rs[64];
    const int tid = threadIdx.x;
    const int wid = blockIdx.x;
    const int b = wid >> 8, hb = (wid >> 4) & 15, wb = wid & 15;
    const int xbase = ((b * 192) << 14) + ((hb * 8) << 7) + wb * 8;
    const int tok0 = wid * 12288;

    for (int idx = tid; idx < 12288; idx += TPB) {
        int c = idx >> 6, l = idx & 63;
        s_x[l * 193 + c] = xrgb[xbase + (c << 14) + ((l >> 3) << 7) + (l & 7)];
    }
    __syncthreads();
    {
        int t = tid >> 2, q4 = tid & 3;
        float sum = 0.f, sq = 0.f;
        for (int j = 0; j < 48; j++) {
            float v = s_x[t * 193 + q4 * 48 + j];
            sum += v; sq += v * v;
        }
        sum += __shfl_xor(sum, 1); sum += __shfl_xor(sum, 2);
        sq  += __shfl_xor(sq, 1);  sq  += __shfl_xor(sq, 2);
        float mu = sum * (1.f / 192.f);
        float var = sq * (1.f / 192.f) - mu * mu;
        if (q4 == 0) { s_mu[t] = mu; s_rs[t] = rsqrtf(var + 1e-6f); }
    }
    __syncthreads();
    for (int idx = tid; idx < 12288; idx += TPB) {
        int t = idx / 192, c = idx - t * 192;
        float x = s_x[t * 193 + c];
        Xg[tok0 + idx] = f2bf(x);
        float xn = (x - s_mu[t]) * s_rs[t];
        Ag[tok0 + idx] = f2bf((xn * ln1w[c] + ln1b[c]) * gamma[b * 192 + c] + beta[b * 192 + c]);
    }
    __syncthreads();
    for (int idx = tid; idx < 12288; idx += TPB) {
        int c = idx >> 6, l = idx & 63;
        s_x[l * 193 + c] = xsar[xbase + (c << 14) + ((l >> 3) << 7) + (l & 7)];
    }
    __syncthreads();
    for (int idx = tid; idx < 12288; idx += TPB) {
        int t = idx / 192, c = idx - t * 192;
        Sg[tok0 + idx] = f2bf(s_x[t * 193 + c]);
    }
}

// ---------------- K2: fused self-attention ----------------
__global__ __launch_bounds__(TPB) void k2_self(
    short* __restrict__ Ag, short* __restrict__ Xg,
    const short* __restrict__ Wqkv, const float* __restrict__ qbp,
    const short* __restrict__ Wap, const float* __restrict__ apb,
    const float* __restrict__ relb,
    const float* __restrict__ ln1w, const float* __restrict__ ln1b,
    const float* __restrict__ gamma, const float* __restrict__ beta)
{
    __shared__ short s_o[12800];   // O, 64 x 200 (192 cols used)
    __shared__ short s_q[2560];    // 64 x 40 (32 cols used, zero-padded d 24..31)
    __shared__ short s_k[2560];
    __shared__ short s_vt[2304];   // 32 x 72 (V transposed: [d][token])
    __shared__ short s_p[4608];    // 64 x 72 (P row-major)
    __shared__ short s_rb[1800];   // rel bias bf16

    const int tid = threadIdx.x;
    const int wid = blockIdx.x;
    const int b = wid >> 8;
    const int mt = tid >> 6;
    const int lane = tid & 63;
    const int g = lane >> 4;
    const int l16 = lane & 15;
    const int fo = lane << 3;         // fragment-tile offset (elements)
    const int tok0 = wid * 12288;
    const int rowA = mt * 16 + l16;
    const int qrow = mt * 16 + g * 4;

    for (int i = tid; i < 1800; i += TPB) s_rb[i] = f2bf(relb[i]);

    const fvec4 z4 = {0.f, 0.f, 0.f, 0.f};

    for (int h = 0; h < 8; h++) {
        // ---- QKV GEMM: M=64 N=96(padded) K=192 ----
        fvec4 acc[6];
#pragma unroll
        for (int i = 0; i < 6; i++) acc[i] = z4;
#pragma unroll
        for (int kt = 0; kt < 6; kt++) {
            bhalf8 af = *(const bhalf8*)&Ag[tok0 + rowA * 192 + kt * 32 + g * 8];
#pragma unroll
            for (int nt = 0; nt < 6; nt++) {
                bhalf8 bf = *(const bhalf8*)&Wqkv[((h * 36 + nt * 6 + kt) << 9) + fo];
                acc[nt] = MFMA(af, bf, acc[nt]);
            }
        }
        __syncthreads();  // prior head's S/PV readers done before overwriting s_q/s_k/s_vt
#pragma unroll
        for (int nt = 0; nt < 6; nt++) {
            float bq = qbp[h * 96 + nt * 16 + l16];
            int d = (nt & 1) * 16 + l16;
#pragma unroll
            for (int r = 0; r < 4; r++) {
                int tok = qrow + r;
                short bv = f2bf(acc[nt][r] + bq);
                if (nt < 2)      s_q[tok * 40 + d] = bv;
                else if (nt < 4) s_k[tok * 40 + d] = bv;
                else             s_vt[d * 72 + tok] = bv;
            }
        }
        __syncthreads();
        // ---- S = Q K^T (K=32 padded, pads are zero) ----
        fvec4 sacc[4];
        {
            bhalf8 qf = *(const bhalf8*)&s_q[rowA * 40 + g * 8];
#pragma unroll
            for (int nt = 0; nt < 4; nt++) {
                bhalf8 kf = *(const bhalf8*)&s_k[(nt * 16 + l16) * 40 + g * 8];
                sacc[nt] = MFMA(qf, kf, z4);
            }
        }
        // ---- scale + rel bias + softmax ----
        float sv[4][4];
#pragma unroll
        for (int nt = 0; nt < 4; nt++) {
            int n = nt * 16 + l16, ki = n >> 3, kj = n & 7;
#pragma unroll
            for (int r = 0; r < 4; r++) {
                int qq = qrow + r, qi = qq >> 3, qj = qq & 7;
                int ridx = (qi - ki + 7) * 15 + (qj - kj + 7);
                sv[nt][r] = sacc[nt][r] * SCALEF + bf2f(s_rb[ridx * 8 + h]);
            }
        }
#pragma unroll
        for (int r = 0; r < 4; r++) {
            float m = fmaxf(fmaxf(sv[0][r], sv[1][r]), fmaxf(sv[2][r], sv[3][r]));
            m = fmaxf(m, __shfl_xor(m, 1)); m = fmaxf(m, __shfl_xor(m, 2));
            m = fmaxf(m, __shfl_xor(m, 4)); m = fmaxf(m, __shfl_xor(m, 8));
            float s = 0.f;
#pragma unroll
            for (int nt = 0; nt < 4; nt++) { sv[nt][r] = __expf(sv[nt][r] - m); s += sv[nt][r]; }
            s += __shfl_xor(s, 1); s += __shfl_xor(s, 2);
            s += __shfl_xor(s, 4); s += __shfl_xor(s, 8);
            float inv = 1.f / s;
#pragma unroll
            for (int nt = 0; nt < 4; nt++) s_p[(qrow + r) * 72 + nt * 16 + l16] = f2bf(sv[nt][r] * inv);
        }
        // ---- O = P V ----
        fvec4 oacc[2];
        oacc[0] = z4; oacc[1] = z4;
#pragma unroll
        for (int ks = 0; ks < 2; ks++) {
            bhalf8 pf = *(const bhalf8*)&s_p[rowA * 72 + ks * 32 + g * 8];
#pragma unroll
            for (int nt = 0; nt < 2; nt++) {
                bhalf8 vf = *(const bhalf8*)&s_vt[(nt * 16 + l16) * 72 + ks * 32 + g * 8];
                oacc[nt] = MFMA(pf, vf, oacc[nt]);
            }
        }
#pragma unroll
        for (int nt = 0; nt < 2; nt++) {
            int d = nt * 16 + l16;
            if (d < 24) {
#pragma unroll
                for (int r = 0; r < 4; r++)
                    s_o[(qrow + r) * 200 + h * 24 + d] = f2bf(oacc[nt][r]);
            }
        }
    }
    // ---- proj: y = O @ apw^T ----
    fvec4 yacc[12];
#pragma unroll
    for (int i = 0; i < 12; i++) yacc[i] = z4;
#pragma unroll
    for (int kt = 0; kt < 6; kt++) {
        bhalf8 of = *(const bhalf8*)&s_o[rowA * 200 + kt * 32 + g * 8];
#pragma unroll
        for (int nt = 0; nt < 12; nt++) {
            bhalf8 wf = *(const bhalf8*)&Wap[((nt * 6 + kt) << 9) + fo];
            yacc[nt] = MFMA(of, wf, yacc[nt]);
        }
    }
    // ---- epilogue: x1 = x_rgb + y + apb ; X=x1, A=cln1(x1) ----
    float sum[4] = {0.f, 0.f, 0.f, 0.f}, sq[4] = {0.f, 0.f, 0.f, 0.f};
#pragma unroll
    for (int nt = 0; nt < 12; nt++) {
        int col = nt * 16 + l16;
        float ap = apb[col];
#pragma unroll
        for (int r = 0; r < 4; r++) {
            int tok = qrow + r;
            float x = bf2f(Xg[tok0 + tok * 192 + col]) + yacc[nt][r] + ap;
            yacc[nt][r] = x;
            sum[r] += x; sq[r] += x * x;
        }
    }
#pragma unroll
    for (int r = 0; r < 4; r++) {
        float s1 = sum[r], s2 = sq[r];
        s1 += __shfl_xor(s1, 1); s1 += __shfl_xor(s1, 2); s1 += __shfl_xor(s1, 4); s1 += __shfl_xor(s1, 8);
        s2 += __shfl_xor(s2, 1); s2 += __shfl_xor(s2, 2); s2 += __shfl_xor(s2, 4); s2 += __shfl_xor(s2, 8);
        float mu = s1 * (1.f / 192.f);
        float var = s2 * (1.f / 192.f) - mu * mu;
        sum[r] = mu; sq[r] = rsqrtf(var + 1e-6f);
    }
#pragma unroll
    for (int nt = 0; nt < 12; nt++) {
        int col = nt * 16 + l16;
        float lw = ln1w[col], lb = ln1b[col], ga = gamma[b * 192 + col], be = beta[b * 192 + col];
#pragma unroll
        for (int r = 0; r < 4; r++) {
            int tok = qrow + r;
            float x = yacc[nt][r];
            Xg[tok0 + tok * 192 + col] = f2bf(x);
            float xn = (x - sum[r]) * sq[r];
            Ag[tok0 + tok * 192 + col] = f2bf((xn * lw + lb) * ga + be);
        }
    }
}

// ---------------- K3: fused cross-attention ----------------
__global__ __launch_bounds__(TPB) void k3_cross(
    short* __restrict__ Ag, short* __restrict__ Xg, const short* __restrict__ Sg,
    const short* __restrict__ Wqc, const short* __restrict__ Wkv,
    const short* __restrict__ Wcp, const float* __restrict__ cpb,
    const float* __restrict__ ln2w, const float* __restrict__ ln2b,
    const float* __restrict__ gamma, const float* __restrict__ beta)
{
    __shared__ short s_o[12800];
    __shared__ short s_q[2560];
    __shared__ short s_k[2560];
    __shared__ short s_vt[2304];
    __shared__ short s_p[4608];

    const int tid = threadIdx.x;
    const int wid = blockIdx.x;
    const int b = wid >> 8;
    const int mt = tid >> 6;
    const int lane = tid & 63;
    const int g = lane >> 4;
    const int l16 = lane & 15;
    const int fo = lane << 3;
    const int tok0 = wid * 12288;
    const int rowA = mt * 16 + l16;
    const int qrow = mt * 16 + g * 4;
    const fvec4 z4 = {0.f, 0.f, 0.f, 0.f};

    for (int h = 0; h < 8; h++) {
        fvec4 accq[2], acckv[4];
        accq[0] = z4; accq[1] = z4;
#pragma unroll
        for (int i = 0; i < 4; i++) acckv[i] = z4;
#pragma unroll
        for (int kt = 0; kt < 6; kt++) {
            bhalf8 af = *(const bhalf8*)&Ag[tok0 + rowA * 192 + kt * 32 + g * 8];
            bhalf8 sf = *(const bhalf8*)&Sg[tok0 + rowA * 192 + kt * 32 + g * 8];
#pragma unroll
            for (int nt = 0; nt < 2; nt++) {
                bhalf8 bf = *(const bhalf8*)&Wqc[((h * 12 + nt * 6 + kt) << 9) + fo];
                accq[nt] = MFMA(af, bf, accq[nt]);
            }
#pragma unroll
            for (int nt = 0; nt < 4; nt++) {
                bhalf8 bf = *(const bhalf8*)&Wkv[((h * 24 + nt * 6 + kt) << 9) + fo];
                acckv[nt] = MFMA(sf, bf, acckv[nt]);
            }
        }
        __syncthreads();
#pragma unroll
        for (int nt = 0; nt < 2; nt++) {
            int d = nt * 16 + l16;
#pragma unroll
            for (int r = 0; r < 4; r++)
                s_q[(qrow + r) * 40 + d] = f2bf(accq[nt][r]);
        }
#pragma unroll
        for (int nt = 0; nt < 4; nt++) {
            int d = (nt & 1) * 16 + l16;
#pragma unroll
            for (int r = 0; r < 4; r++) {
                int tok = qrow + r;
                short bv = f2bf(acckv[nt][r]);
                if (nt < 2) s_k[tok * 40 + d] = bv;
                else        s_vt[d * 72 + tok] = bv;
            }
        }
        __syncthreads();
        fvec4 sacc[4];
        {
            bhalf8 qf = *(const bhalf8*)&s_q[rowA * 40 + g * 8];
#pragma unroll
            for (int nt = 0; nt < 4; nt++) {
                bhalf8 kf = *(const bhalf8*)&s_k[(nt * 16 + l16) * 40 + g * 8];
                sacc[nt] = MFMA(qf, kf, z4);
            }
        }
        float sv[4][4];
#pragma unroll
        for (int nt = 0; nt < 4; nt++)
#pragma unroll
            for (int r = 0; r < 4; r++)
                sv[nt][r] = sacc[nt][r] * SCALEF;
#pragma unroll
        for (int r = 0; r < 4; r++) {
            float m = fmaxf(fmaxf(sv[0][r], sv[1][r]), fmaxf(sv[2][r], sv[3][r]));
            m = fmaxf(m, __shfl_xor(m, 1)); m = fmaxf(m, __shfl_xor(m, 2));
            m = fmaxf(m, __shfl_xor(m, 4)); m = fmaxf(m, __shfl_xor(m, 8));
            float s = 0.f;
#pragma unroll
            for (int nt = 0; nt < 4; nt++) { sv[nt][r] = __expf(sv[nt][r] - m); s += sv[nt][r]; }
            s += __shfl_xor(s, 1); s += __shfl_xor(s, 2);
            s += __shfl_xor(s, 4); s += __shfl_xor(s, 8);
            float inv = 1.f / s;
#pragma unroll
            for (int nt = 0; nt < 4; nt++) s_p[(qrow + r) * 72 + nt * 16 + l16] = f2bf(sv[nt][r] * inv);
        }
        fvec4 oacc[2];
        oacc[0] = z4; oacc[1] = z4;
#pragma unroll
        for (int ks = 0; ks < 2; ks++) {
            bhalf8 pf = *(const bhalf8*)&s_p[rowA * 72 + ks * 32 + g * 8];
#pragma unroll
            for (int nt = 0; nt < 2; nt++) {
                bhalf8 vf = *(const bhalf8*)&s_vt[(nt * 16 + l16) * 72 + ks * 32 + g * 8];
                oacc[nt] = MFMA(pf, vf, oacc[nt]);
            }
        }
#pragma unroll
        for (int nt = 0; nt < 2; nt++) {
            int d = nt * 16 + l16;
            if (d < 24) {
#pragma unroll
                for (int r = 0; r < 4; r++)
                    s_o[(qrow + r) * 200 + h * 24 + d] = f2bf(oacc[nt][r]);
            }
        }
    }
    fvec4 yacc[12];
#pragma unroll
    for (int i = 0; i < 12; i++) yacc[i] = z4;
#pragma unroll
    for (int kt = 0; kt < 6; kt++) {
        bhalf8 of = *(const bhalf8*)&s_o[rowA * 200 + kt * 32 + g * 8];
#pragma unroll
        for (int nt = 0; nt < 12; nt++) {
            bhalf8 wf = *(const bhalf8*)&Wcp[((nt * 6 + kt) << 9) + fo];
            yacc[nt] = MFMA(of, wf, yacc[nt]);
        }
    }
    float sum[4] = {0.f, 0.f, 0.f, 0.f}, sq[4] = {0.f, 0.f, 0.f, 0.f};
#pragma unroll
    for (int nt = 0; nt < 12; nt++) {
        int col = nt * 16 + l16;
        float cp = cpb[col];
#pragma unroll
        for (int r = 0; r < 4; r++) {
            int tok = qrow + r;
            float x = bf2f(Xg[tok0 + tok * 192 + col]) + yacc[nt][r] + cp;
            yacc[nt][r] = x;
            sum[r] += x; sq[r] += x * x;
        }
    }
#pragma unroll
    for (int r = 0; r < 4; r++) {
        float s1 = sum[r], s2 = sq[r];
        s1 += __shfl_xor(s1, 1); s1 += __shfl_xor(s1, 2); s1 += __shfl_xor(s1, 4); s1 += __shfl_xor(s1, 8);
        s2 += __shfl_xor(s2, 1); s2 += __shfl_xor(s2, 2); s2 += __shfl_xor(s2, 4); s2 += __shfl_xor(s2, 8);
        float mu = s1 * (1.f / 192.f);
        float var = s2 * (1.f / 192.f) - mu * mu;
        sum[r] = mu; sq[r] = rsqrtf(var + 1e-6f);
    }
#pragma unroll
    for (int nt = 0; nt < 12; nt++) {
        int col = nt * 16 + l16;
        float lw = ln2w[col], lb = ln2b[col], ga = gamma[b * 192 + col], be = beta[b * 192 + col];
#pragma unroll
        for (int r = 0; r < 4; r++) {
            int tok = qrow + r;
            float x = yacc[nt][r];
            Xg[tok0 + tok * 192 + col] = f2bf(x);
            float xn = (x - sum[r]) * sq[r];
            Ag[tok0 + tok * 192 + col] = f2bf((xn * lw + lb) * ga + be);
        }
    }
}

// ---------------- K4: fused FFN + residual, scatter to NCHW ----------------
// v2: wave-split N, M=64 per wave. Each wave owns a private slice of the
// hidden (GEMM1: 2 of 8 n-tiles per chunk) and output (GEMM2: 3 of 12
// n-tiles) dimension, computing all 64 tokens for that slice. This cuts
// per-wave global weight traffic 4x (576KB -> 144KB) and moves the A-tile
// into LDS (read once from global instead of 6x). The old layout gave each
// wave only M=16 tokens while streaming the full W1+W2 from L2 -> latency
// bound (MfmaUtil 6%).
__global__ __launch_bounds__(TPB) void k4_ffn(
    const short* __restrict__ Ag, const short* __restrict__ Xg,
    const short* __restrict__ W1b, const short* __restrict__ W2b,
    float* __restrict__ out)
{
    __shared__ short s_u[12800];   // union: A-tile 64x200 (GEMMs), then out-tile 64x200
    __shared__ short s_h[12800];   // union: hidden chunk 64x200 (128 used), then Xg stage

    const int tid = threadIdx.x;
    const int wid = blockIdx.x;
    const int b = wid >> 8, hb = (wid >> 4) & 15, wb = wid & 15;
    const int xbase = ((b * 192) << 14) + ((hb * 8) << 7) + wb * 8;
    const int w = tid >> 6;        // wave id 0..3
    const int lane = tid & 63;
    const int g = lane >> 4;
    const int l16 = lane & 15;
    const int fo = lane << 3;
    const int tok0 = wid * 12288;
    const fvec4 z4 = {0.f, 0.f, 0.f, 0.f};

    // ---- stage A (cln2 output) into LDS, vectorized 16B loads ----
    for (int i = tid; i < 1536; i += TPB) {
        int flat = i << 3;
        int t = flat / 192, cc = flat - t * 192;
        *(bhalf8*)&s_u[t * 200 + cc] = *(const bhalf8*)&Ag[tok0 + flat];
    }
    __syncthreads();

    fvec4 yacc[4][3];
#pragma unroll
    for (int mt = 0; mt < 4; mt++)
#pragma unroll
        for (int j = 0; j < 3; j++) yacc[mt][j] = z4;

    for (int c = 0; c < 6; c++) {
        // ---- GEMM1: hidden chunk [c*128, c*128+128); wave owns n-tiles w*2, w*2+1 ----
        fvec4 hacc[4][2];
#pragma unroll
        for (int mt = 0; mt < 4; mt++) { hacc[mt][0] = z4; hacc[mt][1] = z4; }
#pragma unroll
        for (int kt = 0; kt < 6; kt++) {
            bhalf8 af[4];
#pragma unroll
            for (int mt = 0; mt < 4; mt++)
                af[mt] = *(const bhalf8*)&s_u[(mt * 16 + l16) * 200 + kt * 32 + g * 8];
#pragma unroll
            for (int n2 = 0; n2 < 2; n2++) {
                bhalf8 wf = *(const bhalf8*)&W1b[(((c * 8 + w * 2 + n2) * 6 + kt) << 9) + fo];
#pragma unroll
                for (int mt = 0; mt < 4; mt++)
                    hacc[mt][n2] = MFMA(af[mt], wf, hacc[mt][n2]);
            }
        }
        // ---- GELU -> s_h (wave writes its 32 cols, all 64 rows) ----
#pragma unroll
        for (int n2 = 0; n2 < 2; n2++) {
            int cc = w * 32 + n2 * 16 + l16;
#pragma unroll
            for (int mt = 0; mt < 4; mt++) {
#pragma unroll
                for (int r = 0; r < 4; r++) {
                    float x = hacc[mt][n2][r];
                    float gl = 0.5f * x * (1.f + erff(x * 0.70710678118654752f));
                    s_h[(mt * 16 + g * 4 + r) * 200 + cc] = f2bf(gl);
                }
            }
        }
        __syncthreads();
        // ---- GEMM2: K-slice of 128; wave owns output n-tiles 3w..3w+2 ----
#pragma unroll
        for (int ks = 0; ks < 4; ks++) {
            bhalf8 hf[4];
#pragma unroll
            for (int mt = 0; mt < 4; mt++)
                hf[mt] = *(const bhalf8*)&s_h[(mt * 16 + l16) * 200 + ks * 32 + g * 8];
#pragma unroll
            for (int j = 0; j < 3; j++) {
                bhalf8 wf = *(const bhalf8*)&W2b[(((w * 3 + j) * 24 + c * 4 + ks) << 9) + fo];
#pragma unroll
                for (int mt = 0; mt < 4; mt++)
                    yacc[mt][j] = MFMA(hf[mt], wf, yacc[mt][j]);
            }
        }
        __syncthreads();  // all GEMM2 reads of s_h done before next chunk overwrites
    }

    // ---- stage Xg (residual) into s_h, vectorized ----
    for (int i = tid; i < 1536; i += TPB) {
        int flat = i << 3;
        int t = flat / 192, cc = flat - t * 192;
        *(bhalf8*)&s_h[t * 200 + cc] = *(const bhalf8*)&Xg[tok0 + flat];
    }
    __syncthreads();
    // ---- epilogue: residual add, write out-tile (wave owns cols 48w..48w+47) ----
#pragma unroll
    for (int j = 0; j < 3; j++) {
        int col = (w * 3 + j) * 16 + l16;
#pragma unroll
        for (int mt = 0; mt < 4; mt++) {
#pragma unroll
            for (int r = 0; r < 4; r++) {
                int tok = mt * 16 + g * 4 + r;
                float v = bf2f(s_h[tok * 200 + col]) + yacc[mt][j][r];
                s_u[tok * 200 + col] = f2bf(v);
            }
        }
    }
    __syncthreads();
    for (int i = tid; i < 12288; i += TPB) {
        int cc = i >> 6, l = i & 63;
        out[xbase + (cc << 14) + ((l >> 3) << 7) + (l & 7)] = bf2f(s_u[l * 200 + cc]);
    }
}

extern "C" void kernel_launch(void* const* d_in, const int* in_sizes, int n_in,
                              void* d_out, int out_size, void* d_ws, size_t ws_size,
                              hipStream_t stream) {
    const float* xrgb  = (const float*)d_in[0];
    const float* xsar  = (const float*)d_in[1];
    const float* gamma = (const float*)d_in[2];
    const float* beta  = (const float*)d_in[3];
    const float* ln1w  = (const float*)d_in[4];
    const float* ln1b  = (const float*)d_in[5];
    const float* ln2w  = (const float*)d_in[6];
    const float* ln2b  = (const float*)d_in[7];
    const float* qkvw  = (const float*)d_in[8];
    const float* qkvb  = (const float*)d_in[9];
    const float* apw   = (const float*)d_in[10];
    const float* apb   = (const float*)d_in[11];
    const float* relb  = (const float*)d_in[12];
    const float* qw    = (const float*)d_in[13];
    const float* kvw   = (const float*)d_in[14];
    const float* cpw   = (const float*)d_in[15];
    const float* cpb   = (const float*)d_in[16];
    const float* w1    = (const float*)d_in[17];
    const float* w2    = (const float*)d_in[18];

    char* base = (char*)d_ws;
    short* Wqkv = (short*)base;
    short* Wqc  = Wqkv + N_QKV;
    short* Wkv  = Wqc + N_QC;
    short* Wap  = Wkv + N_KV;
    short* Wcp  = Wap + N_AP;
    short* W1b  = Wcp + N_CP;
    short* W2b  = W1b + N_W1;
    float* qbp  = (float*)(base + (size_t)W_TOT * 2);          // 768 floats
    short* Ag   = (short*)(base + (size_t)W_TOT * 2 + 3072);   // 131072 x 192 bf16
    short* Xg   = Ag + 25165824;
    short* Sg   = Xg + 25165824;

    float* out = (float*)d_out;

    hipLaunchKernelGGL(k0_wprep, dim3(256), dim3(TPB), 0, stream,
                       qkvw, qkvb, qw, kvw, apw, cpw, w1, w2,
                       Wqkv, Wqc, Wkv, Wap, Wcp, W1b, W2b, qbp);
    hipLaunchKernelGGL(k1_prep, dim3(NWIN), dim3(TPB), 0, stream,
                       xrgb, xsar, gamma, beta, ln1w, ln1b, Ag, Xg, Sg);
    hipLaunchKernelGGL(k2_self, dim3(NWIN), dim3(TPB), 0, stream,
                       Ag, Xg, Wqkv, qbp, Wap, apb, relb, ln1w, ln1b, gamma, beta);
    hipLaunchKernelGGL(k3_cross, dim3(NWIN), dim3(TPB), 0, stream,
                       Ag, Xg, Sg, Wqc, Wkv, Wcp, cpb, ln2w, ln2b, gamma, beta);
    hipLaunchKernelGGL(k4_ffn, dim3(NWIN), dim3(TPB), 0, stream,
                       Ag, Xg, W1b, W2b, out);
}